// Round 2
// baseline (311.951 us; speedup 1.0000x reference)
//
#include <hip/hip_runtime.h>

// GranularMoELayer: B=8192, D_IN=1024, D_OUT=1024, E=8, K=2, H=2048
// Sparse top-2 routing (atomic-free, deterministic) + bf16 MFMA grouped GEMMs.
// R2: occupancy repair at 128^2 granularity:
//   (a) compact GEMM grids via device-built M-chunk table (no dead-block flood)
//   (b) __launch_bounds__(256,4) to cap regs at 128/wave -> 4 blocks/CU
//   (c) revert R1 dbuf (proven neutral-negative) to single-buffer 2-barrier loop

#define NTOK 8192
#define DIN  1024
#define DOUT 1024
#define NEXP 8
#define NHID 2048
#define NENT (NTOK * 2)          // 16384 routing entries
#define ABLK 64                  // assign/hist blocks (256 entries each)
#define MCHMAX 136               // >= sum_e ceil(count_e/128) (<=135) ; 136%8==0

typedef __bf16 bf16_t;
typedef __bf16 bf16x8 __attribute__((ext_vector_type(8)));
typedef __bf16 bf16x4 __attribute__((ext_vector_type(4)));
typedef float  f32x4  __attribute__((ext_vector_type(4)));

// CK-style address-space casts for global_load_lds
#define AS3(p) ((__attribute__((address_space(3))) void*)(unsigned)(unsigned long long)(p))
#define AS1(p) ((__attribute__((address_space(1))) void*)(unsigned long long)(p))

static __device__ __forceinline__ int imin_(int a, int b) { return a < b ? a : b; }

// XCD-aware bijective swizzle (gridDim.x % 8 == 0): each XCD gets a
// contiguous chunk of logical block ids -> per-expert weight panel L2-resident.
static __device__ __forceinline__ int xcd_swizzle() {
    int cpx = gridDim.x >> 3;
    return (blockIdx.x & 7) * cpx + (blockIdx.x >> 3);
}

// ---------------------------------------------------------------------------
// Transpose + f32->bf16 convert:  W[E][K_][N_] (f32) -> WT[E][N_][K_] (bf16)
// ---------------------------------------------------------------------------
__global__ __launch_bounds__(256) void k_transpose_cvt(
    const float* __restrict__ W, bf16_t* __restrict__ WT, int K_, int N_)
{
    __shared__ float tile[64][65];
    const int tilesK = K_ >> 6, tilesN = N_ >> 6;
    int bid = blockIdx.x;
    int e = bid / (tilesK * tilesN);
    int r = bid % (tilesK * tilesN);
    int tk = (r / tilesN) << 6;
    int tn = (r % tilesN) << 6;
    const float* Wb  = W  + (size_t)e * K_ * N_;
    bf16_t*      WTb = WT + (size_t)e * K_ * N_;
    int lr = threadIdx.x >> 6;   // 0..3
    int lc = threadIdx.x & 63;   // 0..63
#pragma unroll
    for (int i = 0; i < 16; ++i) {
        int row = i * 4 + lr;
        tile[row][lc] = Wb[(size_t)(tk + row) * N_ + tn + lc];
    }
    __syncthreads();
#pragma unroll
    for (int i = 0; i < 16; ++i) {
        int row = i * 4 + lr;
        WTb[(size_t)(tn + row) * K_ + tk + lc] = (bf16_t)tile[lc][row];
    }
}

// ---------------------------------------------------------------------------
// Tiny transpose: Wg[DIN][E] (f32) -> WgT[E][DIN] (f32)
// ---------------------------------------------------------------------------
__global__ __launch_bounds__(256) void k_wgT(
    const float* __restrict__ Wg, float* __restrict__ WgT)
{
    int i = blockIdx.x * 256 + threadIdx.x;
    int d = i >> 3, e = i & 7;
    WgT[e * DIN + d] = Wg[i];
}

// ---------------------------------------------------------------------------
// Gating: scores = x@Wg + bg (f32), top-2 -> topk. NO atomics.
// Fused: writes xb = bf16(x). One wave per token, all loads coalesced.
// ---------------------------------------------------------------------------
__global__ __launch_bounds__(256) void k_gating(
    const float* __restrict__ x, const float* __restrict__ WgT,
    const float* __restrict__ bg, bf16_t* __restrict__ xb,
    int* __restrict__ topk)
{
    int lane = threadIdx.x & 63;
    int tok  = blockIdx.x * 4 + (threadIdx.x >> 6);
    const float* xr  = x  + (size_t)tok * DIN;
    bf16_t*      xbr = xb + (size_t)tok * DIN;

    float4 xv[4];
#pragma unroll
    for (int i = 0; i < 4; ++i) {
        int idx = i * 256 + lane * 4;
        xv[i] = *reinterpret_cast<const float4*>(xr + idx);
        bf16x4 o;
        o[0] = (bf16_t)xv[i].x; o[1] = (bf16_t)xv[i].y;
        o[2] = (bf16_t)xv[i].z; o[3] = (bf16_t)xv[i].w;
        *reinterpret_cast<bf16x4*>(xbr + idx) = o;
    }

    float acc[NEXP];
#pragma unroll
    for (int e = 0; e < NEXP; ++e) {
        const float* we = WgT + (size_t)e * DIN;
        float a = 0.f;
#pragma unroll
        for (int i = 0; i < 4; ++i) {
            int idx = i * 256 + lane * 4;
            float4 w = *reinterpret_cast<const float4*>(we + idx);
            a += xv[i].x * w.x + xv[i].y * w.y + xv[i].z * w.z + xv[i].w * w.w;
        }
        acc[e] = a;
    }

#pragma unroll
    for (int e = 0; e < NEXP; ++e) {
#pragma unroll
        for (int off = 32; off >= 1; off >>= 1) acc[e] += __shfl_xor(acc[e], off);
    }
    if (lane == 0) {
        float s[NEXP];
#pragma unroll
        for (int e = 0; e < NEXP; ++e) s[e] = acc[e] + bg[e];
        int e0 = 0;
        for (int e = 1; e < NEXP; ++e) if (s[e] > s[e0]) e0 = e;   // ties -> lower idx
        int e1 = (e0 == 0) ? 1 : 0;
        for (int e = 0; e < NEXP; ++e) if (e != e0 && s[e] > s[e1]) e1 = e;
        topk[2 * tok]     = e0;
        topk[2 * tok + 1] = e1;
    }
}

// ---------------------------------------------------------------------------
// Per-block histogram of expert ids (LDS atomics only). ABLK blocks x 256.
// ---------------------------------------------------------------------------
__global__ __launch_bounds__(256) void k_hist(
    const int* __restrict__ topk, int* __restrict__ bh)
{
    __shared__ int h[NEXP];
    if (threadIdx.x < NEXP) h[threadIdx.x] = 0;
    __syncthreads();
    int i = blockIdx.x * 256 + threadIdx.x;
    atomicAdd(&h[topk[i]], 1);                 // LDS-scope, cheap
    __syncthreads();
    if (threadIdx.x < NEXP) bh[blockIdx.x * NEXP + threadIdx.x] = h[threadIdx.x];
}

// ---------------------------------------------------------------------------
// Scan: counts[e], offsets[9], per-block bases blockbase[ABLK][E]. 1 block.
// R2: also builds the compact M-chunk table: chtab[n] = (e<<16)|mc for each
// live 128-row chunk; nch[0] = number of live chunks. chtab ALIASES bh
// (bh fully consumed before the table is written).
// ---------------------------------------------------------------------------
__global__ void k_scan2(const int* __restrict__ bh, int* __restrict__ counts,
                        int* __restrict__ offsets, int* __restrict__ blockbase,
                        int* __restrict__ chtab, int* __restrict__ nch)
{
    __shared__ int sc[NEXP], so_[NEXP + 1];
    int t = threadIdx.x;
    if (t < NEXP) {
        int s = 0;
        for (int b = 0; b < ABLK; ++b) s += bh[b * NEXP + t];
        sc[t] = s;
    }
    __syncthreads();
    if (t == 0) {
        int s = 0;
        for (int e = 0; e < NEXP; ++e) { so_[e] = s; s += sc[e]; }
        so_[NEXP] = s;
        for (int e = 0; e <= NEXP; ++e) offsets[e] = so_[e];
        for (int e = 0; e < NEXP; ++e) counts[e] = sc[e];
    }
    __syncthreads();
    if (t < NEXP) {
        int run = so_[t];
        for (int b = 0; b < ABLK; ++b) {
            blockbase[b * NEXP + t] = run;
            run += bh[b * NEXP + t];
        }
    }
    __syncthreads();     // all reads of bh complete before chtab (alias) write
    if (t == 0) {
        int n = 0;
        for (int e = 0; e < NEXP; ++e) {
            int mch = (sc[e] + 127) >> 7;
            for (int m = 0; m < mch; ++m) chtab[n++] = (e << 16) | m;
        }
        nch[0] = n;
    }
}

// ---------------------------------------------------------------------------
// Stable slot assignment via wave ballots (deterministic, atomic-free).
// entry i = (token i>>1, choice i&1). slot s -> token_ids[s]; slot_of[i] = s.
// ---------------------------------------------------------------------------
__global__ __launch_bounds__(256) void k_assign(
    const int* __restrict__ topk, const int* __restrict__ blockbase,
    int* __restrict__ token_ids, int* __restrict__ slot_of)
{
    __shared__ int wcnt[4][NEXP];
    int tid = threadIdx.x, blk = blockIdx.x;
    int i = blk * 256 + tid;
    int e = topk[i];
    int lane = tid & 63, w = tid >> 6;
    unsigned long long ltmask = (1ull << lane) - 1ull;
    int rank_w = 0;
#pragma unroll
    for (int ee = 0; ee < NEXP; ++ee) {
        unsigned long long m = __ballot(e == ee);
        if (ee == e) rank_w = (int)__popcll(m & ltmask);
        if (lane == 0) wcnt[w][ee] = (int)__popcll(m);
    }
    __syncthreads();
    int pre = 0;
    for (int wv = 0; wv < w; ++wv) pre += wcnt[wv][e];
    int s = blockbase[blk * NEXP + e] + pre + rank_w;
    token_ids[s] = i >> 1;
    slot_of[i] = s;
}

// ---------------------------------------------------------------------------
// Grouped GEMM1: h[slot][:] = relu( x[token(slot)][:] @ W1[e] + b1[e] )  (bf16)
// 128x128 tile, BK=32, 4 waves, mfma_f32_16x16x32_bf16, global_load_lds w=16.
// Compact grid: block -> live (e,mc) via chtab; launch_bounds(256,4) caps
// regs at 128/wave for 4 blocks/CU.
// ---------------------------------------------------------------------------
__global__ __launch_bounds__(256, 4) void k_gemm1(
    const bf16_t* __restrict__ xb, const bf16_t* __restrict__ w1t,
    const float* __restrict__ b1, bf16_t* __restrict__ hb,
    const int* __restrict__ token_ids, const int* __restrict__ counts,
    const int* __restrict__ offsets, const int* __restrict__ chtab,
    const int* __restrict__ nch)
{
    int bid   = xcd_swizzle();        // grid = MCHMAX*16 = 2176 (%8==0)
    int chunk = bid >> 4;
    int nc    = bid & 15;
    if (chunk >= nch[0]) return;
    int em = chtab[chunk];
    int e  = em >> 16;
    int mc = em & 0xffff;
    int count = counts[e];
    int base  = offsets[e];

    __shared__ short At[128][32];
    __shared__ short Bt[128][32];

    int t    = threadIdx.x;
    int lane = t & 63;
    int w    = t >> 6;
    int wr   = (w >> 1) * 64;
    int wc   = (w & 1) * 64;

    int r0 = t >> 2;            // 0..63
    int r1 = 64 + r0;           // 64..127
    int c0 = (t & 3) * 8;       // k-offset (elements)

    int row0 = imin_(mc * 128 + r0, count - 1);
    int row1 = imin_(mc * 128 + r1, count - 1);
    const bf16_t* a0 = xb + (size_t)token_ids[base + row0] * DIN + c0;
    const bf16_t* a1 = xb + (size_t)token_ids[base + row1] * DIN + c0;
    const bf16_t* wbase = w1t + (size_t)e * NHID * DIN;
    const bf16_t* bp0 = wbase + (size_t)(nc * 128 + r0) * DIN + c0;
    const bf16_t* bp1 = wbase + (size_t)(nc * 128 + r1) * DIN + c0;

    unsigned lds0 = (unsigned)(t & 192) * 16;     // wave-uniform base, bytes
    unsigned lds1 = 4096u + lds0;

    f32x4 acc[4][4];
#pragma unroll
    for (int m = 0; m < 4; ++m)
#pragma unroll
        for (int n = 0; n < 4; ++n) acc[m][n] = (f32x4){0.f, 0.f, 0.f, 0.f};

    char* AtB = (char*)&At[0][0];
    char* BtB = (char*)&Bt[0][0];

    for (int k0 = 0; k0 < DIN; k0 += 32) {
        __builtin_amdgcn_global_load_lds(AS1(a0 + k0),  AS3(AtB + lds0), 16, 0, 0);
        __builtin_amdgcn_global_load_lds(AS1(a1 + k0),  AS3(AtB + lds1), 16, 0, 0);
        __builtin_amdgcn_global_load_lds(AS1(bp0 + k0), AS3(BtB + lds0), 16, 0, 0);
        __builtin_amdgcn_global_load_lds(AS1(bp1 + k0), AS3(BtB + lds1), 16, 0, 0);
        __syncthreads();

        bf16x8 af[4], bfv[4];
        int kr = (lane >> 4) * 8;
#pragma unroll
        for (int m = 0; m < 4; ++m)
            af[m] = *reinterpret_cast<const bf16x8*>(&At[wr + m * 16 + (lane & 15)][kr]);
#pragma unroll
        for (int n = 0; n < 4; ++n)
            bfv[n] = *reinterpret_cast<const bf16x8*>(&Bt[wc + n * 16 + (lane & 15)][kr]);
#pragma unroll
        for (int m = 0; m < 4; ++m)
#pragma unroll
            for (int n = 0; n < 4; ++n)
                acc[m][n] = __builtin_amdgcn_mfma_f32_16x16x32_bf16(af[m], bfv[n], acc[m][n], 0, 0, 0);
        __syncthreads();
    }

    // epilogue: bias + relu -> bf16.  D layout: col = lane&15, row = (lane>>4)*4 + q
    int cl = lane & 15;
    int rq = (lane >> 4) * 4;
#pragma unroll
    for (int n = 0; n < 4; ++n) {
        int col  = nc * 128 + wc + n * 16 + cl;
        float bias = b1[e * NHID + col];
#pragma unroll
        for (int m = 0; m < 4; ++m) {
            int rbase = mc * 128 + wr + m * 16 + rq;
#pragma unroll
            for (int q = 0; q < 4; ++q) {
                int gr = rbase + q;
                if (gr < count) {
                    float v = acc[m][n][q] + bias;
                    v = v > 0.f ? v : 0.f;
                    hb[(size_t)(base + gr) * NHID + col] = (bf16_t)v;
                }
            }
        }
    }
}

// ---------------------------------------------------------------------------
// Grouped GEMM2: so[slot][:] = h[slot][:] @ W2[e]   (bf16, no bias, no atomics)
// ---------------------------------------------------------------------------
__global__ __launch_bounds__(256, 4) void k_gemm2(
    const bf16_t* __restrict__ hb, const bf16_t* __restrict__ w2t,
    bf16_t* __restrict__ so,
    const int* __restrict__ counts, const int* __restrict__ offsets,
    const int* __restrict__ chtab, const int* __restrict__ nch)
{
    int bid   = xcd_swizzle();        // grid = MCHMAX*8 = 1088 (%8==0)
    int chunk = bid >> 3;
    int nc    = bid & 7;
    if (chunk >= nch[0]) return;
    int em = chtab[chunk];
    int e  = em >> 16;
    int mc = em & 0xffff;
    int count = counts[e];
    int base  = offsets[e];

    __shared__ short At[128][32];
    __shared__ short Bt[128][32];

    int t    = threadIdx.x;
    int lane = t & 63;
    int w    = t >> 6;
    int wr   = (w >> 1) * 64;
    int wc   = (w & 1) * 64;

    int r0 = t >> 2;
    int r1 = 64 + r0;
    int c0 = (t & 3) * 8;

    int row0 = imin_(mc * 128 + r0, count - 1);
    int row1 = imin_(mc * 128 + r1, count - 1);
    const bf16_t* a0 = hb + (size_t)(base + row0) * NHID + c0;
    const bf16_t* a1 = hb + (size_t)(base + row1) * NHID + c0;
    const bf16_t* wbase = w2t + (size_t)e * DOUT * NHID;
    const bf16_t* bp0 = wbase + (size_t)(nc * 128 + r0) * NHID + c0;
    const bf16_t* bp1 = wbase + (size_t)(nc * 128 + r1) * NHID + c0;

    unsigned lds0 = (unsigned)(t & 192) * 16;
    unsigned lds1 = 4096u + lds0;

    f32x4 acc[4][4];
#pragma unroll
    for (int m = 0; m < 4; ++m)
#pragma unroll
        for (int n = 0; n < 4; ++n) acc[m][n] = (f32x4){0.f, 0.f, 0.f, 0.f};

    char* AtB = (char*)&At[0][0];
    char* BtB = (char*)&Bt[0][0];

    for (int k0 = 0; k0 < NHID; k0 += 32) {
        __builtin_amdgcn_global_load_lds(AS1(a0 + k0),  AS3(AtB + lds0), 16, 0, 0);
        __builtin_amdgcn_global_load_lds(AS1(a1 + k0),  AS3(AtB + lds1), 16, 0, 0);
        __builtin_amdgcn_global_load_lds(AS1(bp0 + k0), AS3(BtB + lds0), 16, 0, 0);
        __builtin_amdgcn_global_load_lds(AS1(bp1 + k0), AS3(BtB + lds1), 16, 0, 0);
        __syncthreads();

        bf16x8 af[4], bfv[4];
        int kr = (lane >> 4) * 8;
#pragma unroll
        for (int m = 0; m < 4; ++m)
            af[m] = *reinterpret_cast<const bf16x8*>(&At[wr + m * 16 + (lane & 15)][kr]);
#pragma unroll
        for (int n = 0; n < 4; ++n)
            bfv[n] = *reinterpret_cast<const bf16x8*>(&Bt[wc + n * 16 + (lane & 15)][kr]);
#pragma unroll
        for (int m = 0; m < 4; ++m)
#pragma unroll
            for (int n = 0; n < 4; ++n)
                acc[m][n] = __builtin_amdgcn_mfma_f32_16x16x32_bf16(af[m], bfv[n], acc[m][n], 0, 0, 0);
        __syncthreads();
    }

    int cl = lane & 15;
    int rq = (lane >> 4) * 4;
#pragma unroll
    for (int n = 0; n < 4; ++n) {
        int col = nc * 128 + wc + n * 16 + cl;
#pragma unroll
        for (int m = 0; m < 4; ++m) {
            int rbase = mc * 128 + wr + m * 16 + rq;
#pragma unroll
            for (int q = 0; q < 4; ++q) {
                int gr = rbase + q;
                if (gr < count)
                    so[(size_t)(base + gr) * DOUT + col] = (bf16_t)acc[m][n][q];
            }
        }
    }
}

// ---------------------------------------------------------------------------
// Combine: out[b][:] = so[s0][:] + so[s1][:] + b2[e0][:] + b2[e1][:]
// 2 tokens per block; fully coalesced; writes every output element.
// ---------------------------------------------------------------------------
__global__ __launch_bounds__(256) void k_combine(
    const bf16_t* __restrict__ so, const float* __restrict__ b2,
    const int* __restrict__ topk, const int* __restrict__ slot_of,
    float* __restrict__ out)
{
    int tid = threadIdx.x;
    int tok = blockIdx.x * 2 + (tid >> 7);
    int c0  = (tid & 127) * 8;
    int s0 = slot_of[2 * tok],  s1 = slot_of[2 * tok + 1];
    int e0 = topk[2 * tok],     e1 = topk[2 * tok + 1];
    bf16x8 a = *reinterpret_cast<const bf16x8*>(so + (size_t)s0 * DOUT + c0);
    bf16x8 b = *reinterpret_cast<const bf16x8*>(so + (size_t)s1 * DOUT + c0);
    const float* bb0 = b2 + (size_t)e0 * DOUT + c0;
    const float* bb1 = b2 + (size_t)e1 * DOUT + c0;
    float* op = out + (size_t)tok * DOUT + c0;
    float4 o0, o1;
    o0.x = (float)a[0] + (float)b[0] + bb0[0] + bb1[0];
    o0.y = (float)a[1] + (float)b[1] + bb0[1] + bb1[1];
    o0.z = (float)a[2] + (float)b[2] + bb0[2] + bb1[2];
    o0.w = (float)a[3] + (float)b[3] + bb0[3] + bb1[3];
    o1.x = (float)a[4] + (float)b[4] + bb0[4] + bb1[4];
    o1.y = (float)a[5] + (float)b[5] + bb0[5] + bb1[5];
    o1.z = (float)a[6] + (float)b[6] + bb0[6] + bb1[6];
    o1.w = (float)a[7] + (float)b[7] + bb0[7] + bb1[7];
    *reinterpret_cast<float4*>(op)     = o0;
    *reinterpret_cast<float4*>(op + 4) = o1;
}

// ---------------------------------------------------------------------------
extern "C" void kernel_launch(void* const* d_in, const int* in_sizes, int n_in,
                              void* d_out, int out_size, void* d_ws, size_t ws_size,
                              hipStream_t stream)
{
    const float* x  = (const float*)d_in[0];
    const float* Wg = (const float*)d_in[1];
    const float* bg = (const float*)d_in[2];
    const float* W1 = (const float*)d_in[3];
    const float* b1 = (const float*)d_in[4];
    const float* W2 = (const float*)d_in[5];
    const float* b2 = (const float*)d_in[6];
    float* out = (float*)d_out;

    // workspace layout (bytes)
    char* ws = (char*)d_ws;
    bf16_t* xb        = (bf16_t*)(ws);                 // 16,777,216
    bf16_t* w1t       = (bf16_t*)(ws + 16777216);      // 33,554,432  [e][h][din]
    bf16_t* w2t       = (bf16_t*)(ws + 50331648);      // 33,554,432  [e][dout][h]
    bf16_t* hb        = (bf16_t*)(ws + 83886080);      // 67,108,864
    int*    topk      = (int*)(ws + 150994944);        // 65,536
    int*    counts    = (int*)(ws + 151060480);        // 32
    int*    offsets   = (int*)(ws + 151060544);        // 64
    int*    token_ids = (int*)(ws + 151060608);        // 65,536
    int*    bh        = (int*)(ws + 151126144);        // 2,048
    int*    blockbase = (int*)(ws + 151128192);        // 2,048
    int*    slot_of   = (int*)(ws + 151130240);        // 65,536
    // total: 151,195,776 bytes (~144.2 MiB)

    // chunk table (<=136 ints) + count alias the bh region: bh is fully
    // consumed inside k_scan2 before the table is written.
    int* chtab = bh;            // 136 ints
    int* nch   = bh + MCHMAX;   // 1 int

    // so (bf16 slot outputs, 33.5 MB) reuses xb+w1t region: both are dead
    // by the time k_gemm2 runs (stream-ordered).
    bf16_t* so = (bf16_t*)ws;
    // WgT (32 KB f32) lives in the hb region: hb first written by k_gemm1,
    // after gating finished reading WgT.
    float* wgT = (float*)hb;

    // Wg[din][e] -> wgT[e][din]
    k_wgT<<<(DIN * NEXP) / 256, 256, 0, stream>>>(Wg, wgT);

    // W1[e][din][h] -> w1t[e][h][din];  W2[e][h][dout] -> w2t[e][dout][h]
    k_transpose_cvt<<<NEXP * (DIN / 64) * (NHID / 64), 256, 0, stream>>>(W1, w1t, DIN, NHID);
    k_transpose_cvt<<<NEXP * (NHID / 64) * (DOUT / 64), 256, 0, stream>>>(W2, w2t, NHID, DOUT);

    k_gating<<<NTOK / 4, 256, 0, stream>>>(x, wgT, bg, xb, topk);
    k_hist<<<ABLK, 256, 0, stream>>>(topk, bh);
    k_scan2<<<1, 64, 0, stream>>>(bh, counts, offsets, blockbase, chtab, nch);
    k_assign<<<ABLK, 256, 0, stream>>>(topk, blockbase, token_ids, slot_of);

    k_gemm1<<<MCHMAX * 16, 256, 0, stream>>>(
        xb, w1t, b1, hb, token_ids, counts, offsets, chtab, nch);
    k_gemm2<<<MCHMAX * 8, 256, 0, stream>>>(
        hb, w2t, so, counts, offsets, chtab, nch);
    k_combine<<<NTOK / 2, 256, 0, stream>>>(so, b2, topk, slot_of, out);
}

// Round 3
// 294.278 us; speedup vs baseline: 1.0601x; 1.0601x over previous
//
#include <hip/hip_runtime.h>

// GranularMoELayer: B=8192, D_IN=1024, D_OUT=1024, E=8, K=2, H=2048
// Sparse top-2 routing (atomic-free, deterministic) + bf16 MFMA grouped GEMMs.
// R3: counted-vmcnt triple-buffered K-loop (T4) in both GEMMs:
//     raw s_barrier + s_waitcnt vmcnt(8) -- prefetched tiles stay in flight
//     ACROSS barriers (never drain to 0 in the main loop). 3x16KB LDS buffers.
//     Keeps R2 compact grid + chunk table.

#define NTOK 8192
#define DIN  1024
#define DOUT 1024
#define NEXP 8
#define NHID 2048
#define NENT (NTOK * 2)          // 16384 routing entries
#define ABLK 64                  // assign/hist blocks (256 entries each)
#define MCHMAX 136               // >= sum_e ceil(count_e/128) (<=135) ; 136%8==0

typedef __bf16 bf16_t;
typedef __bf16 bf16x8 __attribute__((ext_vector_type(8)));
typedef __bf16 bf16x4 __attribute__((ext_vector_type(4)));
typedef float  f32x4  __attribute__((ext_vector_type(4)));

// CK-style address-space casts for global_load_lds
#define AS3(p) ((__attribute__((address_space(3))) void*)(unsigned)(unsigned long long)(p))
#define AS1(p) ((__attribute__((address_space(1))) void*)(unsigned long long)(p))

static __device__ __forceinline__ int imin_(int a, int b) { return a < b ? a : b; }

// XCD-aware bijective swizzle (gridDim.x % 8 == 0): each XCD gets a
// contiguous chunk of logical block ids -> per-expert weight panel L2-resident.
static __device__ __forceinline__ int xcd_swizzle() {
    int cpx = gridDim.x >> 3;
    return (blockIdx.x & 7) * cpx + (blockIdx.x >> 3);
}

// ---------------------------------------------------------------------------
// Transpose + f32->bf16 convert:  W[E][K_][N_] (f32) -> WT[E][N_][K_] (bf16)
// ---------------------------------------------------------------------------
__global__ __launch_bounds__(256) void k_transpose_cvt(
    const float* __restrict__ W, bf16_t* __restrict__ WT, int K_, int N_)
{
    __shared__ float tile[64][65];
    const int tilesK = K_ >> 6, tilesN = N_ >> 6;
    int bid = blockIdx.x;
    int e = bid / (tilesK * tilesN);
    int r = bid % (tilesK * tilesN);
    int tk = (r / tilesN) << 6;
    int tn = (r % tilesN) << 6;
    const float* Wb  = W  + (size_t)e * K_ * N_;
    bf16_t*      WTb = WT + (size_t)e * K_ * N_;
    int lr = threadIdx.x >> 6;   // 0..3
    int lc = threadIdx.x & 63;   // 0..63
#pragma unroll
    for (int i = 0; i < 16; ++i) {
        int row = i * 4 + lr;
        tile[row][lc] = Wb[(size_t)(tk + row) * N_ + tn + lc];
    }
    __syncthreads();
#pragma unroll
    for (int i = 0; i < 16; ++i) {
        int row = i * 4 + lr;
        WTb[(size_t)(tn + row) * K_ + tk + lc] = (bf16_t)tile[lc][row];
    }
}

// ---------------------------------------------------------------------------
// Tiny transpose: Wg[DIN][E] (f32) -> WgT[E][DIN] (f32)
// ---------------------------------------------------------------------------
__global__ __launch_bounds__(256) void k_wgT(
    const float* __restrict__ Wg, float* __restrict__ WgT)
{
    int i = blockIdx.x * 256 + threadIdx.x;
    int d = i >> 3, e = i & 7;
    WgT[e * DIN + d] = Wg[i];
}

// ---------------------------------------------------------------------------
// Gating: scores = x@Wg + bg (f32), top-2 -> topk. NO atomics.
// Fused: writes xb = bf16(x). One wave per token, all loads coalesced.
// ---------------------------------------------------------------------------
__global__ __launch_bounds__(256) void k_gating(
    const float* __restrict__ x, const float* __restrict__ WgT,
    const float* __restrict__ bg, bf16_t* __restrict__ xb,
    int* __restrict__ topk)
{
    int lane = threadIdx.x & 63;
    int tok  = blockIdx.x * 4 + (threadIdx.x >> 6);
    const float* xr  = x  + (size_t)tok * DIN;
    bf16_t*      xbr = xb + (size_t)tok * DIN;

    float4 xv[4];
#pragma unroll
    for (int i = 0; i < 4; ++i) {
        int idx = i * 256 + lane * 4;
        xv[i] = *reinterpret_cast<const float4*>(xr + idx);
        bf16x4 o;
        o[0] = (bf16_t)xv[i].x; o[1] = (bf16_t)xv[i].y;
        o[2] = (bf16_t)xv[i].z; o[3] = (bf16_t)xv[i].w;
        *reinterpret_cast<bf16x4*>(xbr + idx) = o;
    }

    float acc[NEXP];
#pragma unroll
    for (int e = 0; e < NEXP; ++e) {
        const float* we = WgT + (size_t)e * DIN;
        float a = 0.f;
#pragma unroll
        for (int i = 0; i < 4; ++i) {
            int idx = i * 256 + lane * 4;
            float4 w = *reinterpret_cast<const float4*>(we + idx);
            a += xv[i].x * w.x + xv[i].y * w.y + xv[i].z * w.z + xv[i].w * w.w;
        }
        acc[e] = a;
    }

#pragma unroll
    for (int e = 0; e < NEXP; ++e) {
#pragma unroll
        for (int off = 32; off >= 1; off >>= 1) acc[e] += __shfl_xor(acc[e], off);
    }
    if (lane == 0) {
        float s[NEXP];
#pragma unroll
        for (int e = 0; e < NEXP; ++e) s[e] = acc[e] + bg[e];
        int e0 = 0;
        for (int e = 1; e < NEXP; ++e) if (s[e] > s[e0]) e0 = e;   // ties -> lower idx
        int e1 = (e0 == 0) ? 1 : 0;
        for (int e = 0; e < NEXP; ++e) if (e != e0 && s[e] > s[e1]) e1 = e;
        topk[2 * tok]     = e0;
        topk[2 * tok + 1] = e1;
    }
}

// ---------------------------------------------------------------------------
// Per-block histogram of expert ids (LDS atomics only). ABLK blocks x 256.
// ---------------------------------------------------------------------------
__global__ __launch_bounds__(256) void k_hist(
    const int* __restrict__ topk, int* __restrict__ bh)
{
    __shared__ int h[NEXP];
    if (threadIdx.x < NEXP) h[threadIdx.x] = 0;
    __syncthreads();
    int i = blockIdx.x * 256 + threadIdx.x;
    atomicAdd(&h[topk[i]], 1);                 // LDS-scope, cheap
    __syncthreads();
    if (threadIdx.x < NEXP) bh[blockIdx.x * NEXP + threadIdx.x] = h[threadIdx.x];
}

// ---------------------------------------------------------------------------
// Scan: counts[e], offsets[9], per-block bases blockbase[ABLK][E]. 1 block.
// Also builds the compact M-chunk table: chtab[n] = (e<<16)|mc for each
// live 128-row chunk; nch[0] = number of live chunks. chtab ALIASES bh
// (bh fully consumed before the table is written).
// ---------------------------------------------------------------------------
__global__ void k_scan2(const int* __restrict__ bh, int* __restrict__ counts,
                        int* __restrict__ offsets, int* __restrict__ blockbase,
                        int* __restrict__ chtab, int* __restrict__ nch)
{
    __shared__ int sc[NEXP], so_[NEXP + 1];
    int t = threadIdx.x;
    if (t < NEXP) {
        int s = 0;
        for (int b = 0; b < ABLK; ++b) s += bh[b * NEXP + t];
        sc[t] = s;
    }
    __syncthreads();
    if (t == 0) {
        int s = 0;
        for (int e = 0; e < NEXP; ++e) { so_[e] = s; s += sc[e]; }
        so_[NEXP] = s;
        for (int e = 0; e <= NEXP; ++e) offsets[e] = so_[e];
        for (int e = 0; e < NEXP; ++e) counts[e] = sc[e];
    }
    __syncthreads();
    if (t < NEXP) {
        int run = so_[t];
        for (int b = 0; b < ABLK; ++b) {
            blockbase[b * NEXP + t] = run;
            run += bh[b * NEXP + t];
        }
    }
    __syncthreads();     // all reads of bh complete before chtab (alias) write
    if (t == 0) {
        int n = 0;
        for (int e = 0; e < NEXP; ++e) {
            int mch = (sc[e] + 127) >> 7;
            for (int m = 0; m < mch; ++m) chtab[n++] = (e << 16) | m;
        }
        nch[0] = n;
    }
}

// ---------------------------------------------------------------------------
// Stable slot assignment via wave ballots (deterministic, atomic-free).
// entry i = (token i>>1, choice i&1). slot s -> token_ids[s]; slot_of[i] = s.
// ---------------------------------------------------------------------------
__global__ __launch_bounds__(256) void k_assign(
    const int* __restrict__ topk, const int* __restrict__ blockbase,
    int* __restrict__ token_ids, int* __restrict__ slot_of)
{
    __shared__ int wcnt[4][NEXP];
    int tid = threadIdx.x, blk = blockIdx.x;
    int i = blk * 256 + tid;
    int e = topk[i];
    int lane = tid & 63, w = tid >> 6;
    unsigned long long ltmask = (1ull << lane) - 1ull;
    int rank_w = 0;
#pragma unroll
    for (int ee = 0; ee < NEXP; ++ee) {
        unsigned long long m = __ballot(e == ee);
        if (ee == e) rank_w = (int)__popcll(m & ltmask);
        if (lane == 0) wcnt[w][ee] = (int)__popcll(m);
    }
    __syncthreads();
    int pre = 0;
    for (int wv = 0; wv < w; ++wv) pre += wcnt[wv][e];
    int s = blockbase[blk * NEXP + e] + pre + rank_w;
    token_ids[s] = i >> 1;
    slot_of[i] = s;
}

// ---------------------------------------------------------------------------
// Grouped GEMM1: h[slot][:] = relu( x[token(slot)][:] @ W1[e] + b1[e] )  (bf16)
// 128x128 tile, BK=32, 4 waves, mfma_f32_16x16x32_bf16, global_load_lds w=16.
// R3 pipeline: 3 LDS buffers; stage tile kt+2 each iter; counted vmcnt(8);
// raw s_barriers; loads never drained to 0 in the main loop.
// ---------------------------------------------------------------------------
__global__ __launch_bounds__(256, 3) void k_gemm1(
    const bf16_t* __restrict__ xb, const bf16_t* __restrict__ w1t,
    const float* __restrict__ b1, bf16_t* __restrict__ hb,
    const int* __restrict__ token_ids, const int* __restrict__ counts,
    const int* __restrict__ offsets, const int* __restrict__ chtab,
    const int* __restrict__ nch)
{
    int bid   = xcd_swizzle();        // grid = MCHMAX*16 = 2176 (%8==0)
    int chunk = bid >> 4;
    int nc    = bid & 15;
    if (chunk >= nch[0]) return;
    int em = chtab[chunk];
    int e  = em >> 16;
    int mc = em & 0xffff;
    int count = counts[e];
    int base  = offsets[e];

    __shared__ short At[3][128][32];   // 3 x 8 KB
    __shared__ short Bt[3][128][32];   // 3 x 8 KB

    int t    = threadIdx.x;
    int lane = t & 63;
    int w    = t >> 6;
    int wr   = (w >> 1) * 64;
    int wc   = (w & 1) * 64;

    int r0 = t >> 2;            // 0..63
    int r1 = 64 + r0;           // 64..127
    int c0 = (t & 3) * 8;       // k-offset (elements)

    int row0 = imin_(mc * 128 + r0, count - 1);
    int row1 = imin_(mc * 128 + r1, count - 1);
    const bf16_t* a0 = xb + (size_t)token_ids[base + row0] * DIN + c0;
    const bf16_t* a1 = xb + (size_t)token_ids[base + row1] * DIN + c0;
    const bf16_t* wbase = w1t + (size_t)e * NHID * DIN;
    const bf16_t* bp0 = wbase + (size_t)(nc * 128 + r0) * DIN + c0;
    const bf16_t* bp1 = wbase + (size_t)(nc * 128 + r1) * DIN + c0;

    unsigned lds0 = (unsigned)(t & 192) * 16;     // wave-uniform base, bytes
    unsigned lds1 = 4096u + lds0;

    f32x4 acc[4][4];
#pragma unroll
    for (int m = 0; m < 4; ++m)
#pragma unroll
        for (int n = 0; n < 4; ++n) acc[m][n] = (f32x4){0.f, 0.f, 0.f, 0.f};

    char* AtB = (char*)&At[0][0][0];
    char* BtB = (char*)&Bt[0][0][0];

#define STAGE1(buf, koff) do {                                                                     \
    unsigned bo_ = (unsigned)(buf) * 8192u;                                                        \
    __builtin_amdgcn_global_load_lds(AS1(a0  + (koff)), AS3(AtB + bo_ + lds0), 16, 0, 0);          \
    __builtin_amdgcn_global_load_lds(AS1(a1  + (koff)), AS3(AtB + bo_ + lds1), 16, 0, 0);          \
    __builtin_amdgcn_global_load_lds(AS1(bp0 + (koff)), AS3(BtB + bo_ + lds0), 16, 0, 0);          \
    __builtin_amdgcn_global_load_lds(AS1(bp1 + (koff)), AS3(BtB + bo_ + lds1), 16, 0, 0);          \
  } while (0)

    constexpr int NK = DIN / 32;    // 32 K-steps
    // prologue: tiles 0 and 1 in flight
    STAGE1(0, 0);
    STAGE1(1, 32);
    int cc = 0;                     // compute buffer
    int cs = 2;                     // stage buffer (freed last iter / unused)

    for (int kt = 0; kt < NK; ++kt) {
        if (kt + 2 < NK) {
            STAGE1(cs, (kt + 2) * 32);
            asm volatile("s_waitcnt vmcnt(8)" ::: "memory");   // tile kt landed
        } else if (kt + 2 == NK) {
            asm volatile("s_waitcnt vmcnt(4)" ::: "memory");
        } else {
            asm volatile("s_waitcnt vmcnt(0)" ::: "memory");
        }
        __builtin_amdgcn_s_barrier();   // all waves' tile-kt loads landed

        bf16x8 af[4], bfv[4];
        int kr = (lane >> 4) * 8;
#pragma unroll
        for (int m = 0; m < 4; ++m)
            af[m] = *reinterpret_cast<const bf16x8*>(&At[cc][wr + m * 16 + (lane & 15)][kr]);
#pragma unroll
        for (int n = 0; n < 4; ++n)
            bfv[n] = *reinterpret_cast<const bf16x8*>(&Bt[cc][wc + n * 16 + (lane & 15)][kr]);
#pragma unroll
        for (int m = 0; m < 4; ++m)
#pragma unroll
            for (int n = 0; n < 4; ++n)
                acc[m][n] = __builtin_amdgcn_mfma_f32_16x16x32_bf16(af[m], bfv[n], acc[m][n], 0, 0, 0);

        __builtin_amdgcn_s_barrier();   // all waves done READING buffer cc ->
                                        // it becomes next iter's stage target
        cs = cc;
        cc = (cc == 2) ? 0 : cc + 1;
    }
#undef STAGE1

    // epilogue: bias + relu -> bf16.  D layout: col = lane&15, row = (lane>>4)*4 + q
    int cl = lane & 15;
    int rq = (lane >> 4) * 4;
#pragma unroll
    for (int n = 0; n < 4; ++n) {
        int col  = nc * 128 + wc + n * 16 + cl;
        float bias = b1[e * NHID + col];
#pragma unroll
        for (int m = 0; m < 4; ++m) {
            int rbase = mc * 128 + wr + m * 16 + rq;
#pragma unroll
            for (int q = 0; q < 4; ++q) {
                int gr = rbase + q;
                if (gr < count) {
                    float v = acc[m][n][q] + bias;
                    v = v > 0.f ? v : 0.f;
                    hb[(size_t)(base + gr) * NHID + col] = (bf16_t)v;
                }
            }
        }
    }
}

// ---------------------------------------------------------------------------
// Grouped GEMM2: so[slot][:] = h[slot][:] @ W2[e]   (bf16, no bias, no atomics)
// Same R3 counted-vmcnt pipeline, NK = 64.
// ---------------------------------------------------------------------------
__global__ __launch_bounds__(256, 3) void k_gemm2(
    const bf16_t* __restrict__ hb, const bf16_t* __restrict__ w2t,
    bf16_t* __restrict__ so,
    const int* __restrict__ counts, const int* __restrict__ offsets,
    const int* __restrict__ chtab, const int* __restrict__ nch)
{
    int bid   = xcd_swizzle();        // grid = MCHMAX*8 = 1088 (%8==0)
    int chunk = bid >> 3;
    int nc    = bid & 7;
    if (chunk >= nch[0]) return;
    int em = chtab[chunk];
    int e  = em >> 16;
    int mc = em & 0xffff;
    int count = counts[e];
    int base  = offsets[e];

    __shared__ short At[3][128][32];
    __shared__ short Bt[3][128][32];

    int t    = threadIdx.x;
    int lane = t & 63;
    int w    = t >> 6;
    int wr   = (w >> 1) * 64;
    int wc   = (w & 1) * 64;

    int r0 = t >> 2;
    int r1 = 64 + r0;
    int c0 = (t & 3) * 8;

    int row0 = imin_(mc * 128 + r0, count - 1);
    int row1 = imin_(mc * 128 + r1, count - 1);
    const bf16_t* a0 = hb + (size_t)(base + row0) * NHID + c0;
    const bf16_t* a1 = hb + (size_t)(base + row1) * NHID + c0;
    const bf16_t* wbase = w2t + (size_t)e * DOUT * NHID;
    const bf16_t* bp0 = wbase + (size_t)(nc * 128 + r0) * NHID + c0;
    const bf16_t* bp1 = wbase + (size_t)(nc * 128 + r1) * NHID + c0;

    unsigned lds0 = (unsigned)(t & 192) * 16;
    unsigned lds1 = 4096u + lds0;

    f32x4 acc[4][4];
#pragma unroll
    for (int m = 0; m < 4; ++m)
#pragma unroll
        for (int n = 0; n < 4; ++n) acc[m][n] = (f32x4){0.f, 0.f, 0.f, 0.f};

    char* AtB = (char*)&At[0][0][0];
    char* BtB = (char*)&Bt[0][0][0];

#define STAGE2(buf, koff) do {                                                                     \
    unsigned bo_ = (unsigned)(buf) * 8192u;                                                        \
    __builtin_amdgcn_global_load_lds(AS1(a0  + (koff)), AS3(AtB + bo_ + lds0), 16, 0, 0);          \
    __builtin_amdgcn_global_load_lds(AS1(a1  + (koff)), AS3(AtB + bo_ + lds1), 16, 0, 0);          \
    __builtin_amdgcn_global_load_lds(AS1(bp0 + (koff)), AS3(BtB + bo_ + lds0), 16, 0, 0);          \
    __builtin_amdgcn_global_load_lds(AS1(bp1 + (koff)), AS3(BtB + bo_ + lds1), 16, 0, 0);          \
  } while (0)

    constexpr int NK = NHID / 32;   // 64 K-steps
    STAGE2(0, 0);
    STAGE2(1, 32);
    int cc = 0;
    int cs = 2;

    for (int kt = 0; kt < NK; ++kt) {
        if (kt + 2 < NK) {
            STAGE2(cs, (kt + 2) * 32);
            asm volatile("s_waitcnt vmcnt(8)" ::: "memory");
        } else if (kt + 2 == NK) {
            asm volatile("s_waitcnt vmcnt(4)" ::: "memory");
        } else {
            asm volatile("s_waitcnt vmcnt(0)" ::: "memory");
        }
        __builtin_amdgcn_s_barrier();

        bf16x8 af[4], bfv[4];
        int kr = (lane >> 4) * 8;
#pragma unroll
        for (int m = 0; m < 4; ++m)
            af[m] = *reinterpret_cast<const bf16x8*>(&At[cc][wr + m * 16 + (lane & 15)][kr]);
#pragma unroll
        for (int n = 0; n < 4; ++n)
            bfv[n] = *reinterpret_cast<const bf16x8*>(&Bt[cc][wc + n * 16 + (lane & 15)][kr]);
#pragma unroll
        for (int m = 0; m < 4; ++m)
#pragma unroll
            for (int n = 0; n < 4; ++n)
                acc[m][n] = __builtin_amdgcn_mfma_f32_16x16x32_bf16(af[m], bfv[n], acc[m][n], 0, 0, 0);

        __builtin_amdgcn_s_barrier();
        cs = cc;
        cc = (cc == 2) ? 0 : cc + 1;
    }
#undef STAGE2

    int cl = lane & 15;
    int rq = (lane >> 4) * 4;
#pragma unroll
    for (int n = 0; n < 4; ++n) {
        int col = nc * 128 + wc + n * 16 + cl;
#pragma unroll
        for (int m = 0; m < 4; ++m) {
            int rbase = mc * 128 + wr + m * 16 + rq;
#pragma unroll
            for (int q = 0; q < 4; ++q) {
                int gr = rbase + q;
                if (gr < count)
                    so[(size_t)(base + gr) * DOUT + col] = (bf16_t)acc[m][n][q];
            }
        }
    }
}

// ---------------------------------------------------------------------------
// Combine: out[b][:] = so[s0][:] + so[s1][:] + b2[e0][:] + b2[e1][:]
// 2 tokens per block; fully coalesced; writes every output element.
// ---------------------------------------------------------------------------
__global__ __launch_bounds__(256) void k_combine(
    const bf16_t* __restrict__ so, const float* __restrict__ b2,
    const int* __restrict__ topk, const int* __restrict__ slot_of,
    float* __restrict__ out)
{
    int tid = threadIdx.x;
    int tok = blockIdx.x * 2 + (tid >> 7);
    int c0  = (tid & 127) * 8;
    int s0 = slot_of[2 * tok],  s1 = slot_of[2 * tok + 1];
    int e0 = topk[2 * tok],     e1 = topk[2 * tok + 1];
    bf16x8 a = *reinterpret_cast<const bf16x8*>(so + (size_t)s0 * DOUT + c0);
    bf16x8 b = *reinterpret_cast<const bf16x8*>(so + (size_t)s1 * DOUT + c0);
    const float* bb0 = b2 + (size_t)e0 * DOUT + c0;
    const float* bb1 = b2 + (size_t)e1 * DOUT + c0;
    float* op = out + (size_t)tok * DOUT + c0;
    float4 o0, o1;
    o0.x = (float)a[0] + (float)b[0] + bb0[0] + bb1[0];
    o0.y = (float)a[1] + (float)b[1] + bb0[1] + bb1[1];
    o0.z = (float)a[2] + (float)b[2] + bb0[2] + bb1[2];
    o0.w = (float)a[3] + (float)b[3] + bb0[3] + bb1[3];
    o1.x = (float)a[4] + (float)b[4] + bb0[4] + bb1[4];
    o1.y = (float)a[5] + (float)b[5] + bb0[5] + bb1[5];
    o1.z = (float)a[6] + (float)b[6] + bb0[6] + bb1[6];
    o1.w = (float)a[7] + (float)b[7] + bb0[7] + bb1[7];
    *reinterpret_cast<float4*>(op)     = o0;
    *reinterpret_cast<float4*>(op + 4) = o1;
}

// ---------------------------------------------------------------------------
extern "C" void kernel_launch(void* const* d_in, const int* in_sizes, int n_in,
                              void* d_out, int out_size, void* d_ws, size_t ws_size,
                              hipStream_t stream)
{
    const float* x  = (const float*)d_in[0];
    const float* Wg = (const float*)d_in[1];
    const float* bg = (const float*)d_in[2];
    const float* W1 = (const float*)d_in[3];
    const float* b1 = (const float*)d_in[4];
    const float* W2 = (const float*)d_in[5];
    const float* b2 = (const float*)d_in[6];
    float* out = (float*)d_out;

    // workspace layout (bytes)
    char* ws = (char*)d_ws;
    bf16_t* xb        = (bf16_t*)(ws);                 // 16,777,216
    bf16_t* w1t       = (bf16_t*)(ws + 16777216);      // 33,554,432  [e][h][din]
    bf16_t* w2t       = (bf16_t*)(ws + 50331648);      // 33,554,432  [e][dout][h]
    bf16_t* hb        = (bf16_t*)(ws + 83886080);      // 67,108,864
    int*    topk      = (int*)(ws + 150994944);        // 65,536
    int*    counts    = (int*)(ws + 151060480);        // 32
    int*    offsets   = (int*)(ws + 151060544);        // 64
    int*    token_ids = (int*)(ws + 151060608);        // 65,536
    int*    bh        = (int*)(ws + 151126144);        // 2,048
    int*    blockbase = (int*)(ws + 151128192);        // 2,048
    int*    slot_of   = (int*)(ws + 151130240);        // 65,536
    // total: 151,195,776 bytes (~144.2 MiB)

    // chunk table (<=136 ints) + count alias the bh region: bh is fully
    // consumed inside k_scan2 before the table is written.
    int* chtab = bh;            // 136 ints
    int* nch   = bh + MCHMAX;   // 1 int

    // so (bf16 slot outputs, 33.5 MB) reuses xb+w1t region: both are dead
    // by the time k_gemm2 runs (stream-ordered).
    bf16_t* so = (bf16_t*)ws;
    // WgT (32 KB f32) lives in the hb region: hb first written by k_gemm1,
    // after gating finished reading WgT.
    float* wgT = (float*)hb;

    // Wg[din][e] -> wgT[e][din]
    k_wgT<<<(DIN * NEXP) / 256, 256, 0, stream>>>(Wg, wgT);

    // W1[e][din][h] -> w1t[e][h][din];  W2[e][h][dout] -> w2t[e][dout][h]
    k_transpose_cvt<<<NEXP * (DIN / 64) * (NHID / 64), 256, 0, stream>>>(W1, w1t, DIN, NHID);
    k_transpose_cvt<<<NEXP * (NHID / 64) * (DOUT / 64), 256, 0, stream>>>(W2, w2t, NHID, DOUT);

    k_gating<<<NTOK / 4, 256, 0, stream>>>(x, wgT, bg, xb, topk);
    k_hist<<<ABLK, 256, 0, stream>>>(topk, bh);
    k_scan2<<<1, 64, 0, stream>>>(bh, counts, offsets, blockbase, chtab, nch);
    k_assign<<<ABLK, 256, 0, stream>>>(topk, blockbase, token_ids, slot_of);

    k_gemm1<<<MCHMAX * 16, 256, 0, stream>>>(
        xb, w1t, b1, hb, token_ids, counts, offsets, chtab, nch);
    k_gemm2<<<MCHMAX * 8, 256, 0, stream>>>(
        hb, w2t, so, counts, offsets, chtab, nch);
    k_combine<<<NTOK / 2, 256, 0, stream>>>(so, b2, topk, slot_of, out);
}